// Round 5
// baseline (334.187 us; speedup 1.0000x reference)
//
#include <hip/hip_runtime.h>
#include <math.h>

#define NB 4
#define NC 4
#define NF 257
#define NFR 1024
#define NTOT (NB * NC * NF * NFR)
#define NBC (NB * NC)
#define EPSV 1e-3f
#define EPS_MODEL 1e-5f
#define NCHUNK 32

typedef float v2f __attribute__((ext_vector_type(2)));

// Module-scope scratch: allocated at load, graph-capture safe, fully
// rewritten every call.
__device__ float g_Spart[NCHUNK * NBC * NFR];  // partial column sums
__device__ float g_S[NBC * NFR];               // S[b,c,n] = sum_f |X[b,c,f,n]|^2
__device__ float g_gP[96];                     // g_e, P_e per (b,c), e=0..2

// upper-triangle pair index for 4 channels: (0,1)=0 (0,2)=1 (0,3)=2 (1,2)=3 (1,3)=4 (2,3)=5
__host__ __device__ constexpr int PIDX(int s, int t) {
  return 3 * s - (s * (s - 1)) / 2 + (t - s - 1);
}

// Wave-wide sum via DPP (VALU pipe, no LDS traffic). Lane 63 holds the sum.
__device__ __forceinline__ float dpp_red_sum(float v) {
  v += __int_as_float(__builtin_amdgcn_update_dpp(0, __float_as_int(v), 0x111, 0xf, 0xf, true)); // row_shr:1
  v += __int_as_float(__builtin_amdgcn_update_dpp(0, __float_as_int(v), 0x112, 0xf, 0xf, true)); // row_shr:2
  v += __int_as_float(__builtin_amdgcn_update_dpp(0, __float_as_int(v), 0x114, 0xf, 0xf, true)); // row_shr:4
  v += __int_as_float(__builtin_amdgcn_update_dpp(0, __float_as_int(v), 0x118, 0xf, 0xf, true)); // row_shr:8
  v += __int_as_float(__builtin_amdgcn_update_dpp(0, __float_as_int(v), 0x142, 0xa, 0xf, true)); // row_bcast:15
  v += __int_as_float(__builtin_amdgcn_update_dpp(0, __float_as_int(v), 0x143, 0xc, 0xf, true)); // row_bcast:31
  return v;
}

// ---------------------------------------------------------------------------
// K1: partial column sums, float4-vectorized, 512 blocks (full GPU).
// ---------------------------------------------------------------------------
__global__ __launch_bounds__(256) void k_colsum(const float* __restrict__ Xr,
                                                const float* __restrict__ Xi) {
  int u = blockIdx.x * 256 + threadIdx.x;  // bc*256 + q
  int fc = blockIdx.y;
  int f0 = fc * 9;
  int f1 = f0 + 9; if (f1 > NF) f1 = NF;
  int bc = u >> 8, q = u & 255;
  float4 s = make_float4(0.f, 0.f, 0.f, 0.f);
  for (int f = f0; f < f1; ++f) {
    float4 a = reinterpret_cast<const float4*>(Xr + (bc * NF + f) * NFR)[q];
    float4 b = reinterpret_cast<const float4*>(Xi + (bc * NF + f) * NFR)[q];
    s.x += a.x * a.x + b.x * b.x;
    s.y += a.y * a.y + b.y * b.y;
    s.z += a.z * a.z + b.z * b.z;
    s.w += a.w * a.w + b.w * b.w;
  }
  reinterpret_cast<float4*>(g_Spart + fc * (NBC * NFR) + bc * NFR)[q] = s;
}

// ---------------------------------------------------------------------------
// K2 (fused): reduce 32 partials -> g_S; block-reduce to s0; g_e/P_e table.
// ---------------------------------------------------------------------------
__global__ __launch_bounds__(256) void k_redgp() {
  int bc = blockIdx.x, tid = threadIdx.x;
  float4 s = make_float4(0.f, 0.f, 0.f, 0.f);
#pragma unroll
  for (int fc = 0; fc < NCHUNK; ++fc) {
    float4 a = reinterpret_cast<const float4*>(g_Spart + fc * (NBC * NFR) + bc * NFR)[tid];
    s.x += a.x; s.y += a.y; s.z += a.z; s.w += a.w;
  }
  reinterpret_cast<float4*>(g_S + bc * NFR)[tid] = s;
  float p = dpp_red_sum(s.x + s.y + s.z + s.w);
  __shared__ float r[4];
  if ((tid & 63) == 63) r[tid >> 6] = p;
  __syncthreads();
  if (tid == 0) {
    float s0 = (r[0] + r[1] + r[2] + r[3]) / (float)(NF * NFR);
    float P = 1.f;
#pragma unroll
    for (int e = 0; e < 3; ++e) {
      float g = fmaxf(s0 / P, 1e-5f);
      g_gP[e * 32 + bc] = g;
      g_gP[e * 32 + 16 + bc] = P;
      P *= g;
    }
  }
}

// Block-level reduction of N partials (in place), 2-wave version: DPP within
// wave, one barrier, b128 LDS round-trip, double-buffered via `buf`.
template <int N>
__device__ __forceinline__ void block_reduceN(float* p, float (*red)[2][64],
                                              int buf, int lane, int wvid) {
#pragma unroll
  for (int k = 0; k < N; ++k) p[k] = dpp_red_sum(p[k]);
  if (lane == 63) {
    float4* dst = reinterpret_cast<float4*>(&red[buf][wvid][0]);
#pragma unroll
    for (int k = 0; k < N / 4; ++k)
      dst[k] = make_float4(p[4 * k], p[4 * k + 1], p[4 * k + 2], p[4 * k + 3]);
  }
  __syncthreads();
  const float4* r0 = reinterpret_cast<const float4*>(&red[buf][0][0]);
  const float4* r1 = reinterpret_cast<const float4*>(&red[buf][1][0]);
#pragma unroll
  for (int k = 0; k < N / 4; ++k) {
    float4 a = r0[k], b = r1[k];
    p[4 * k + 0] = a.x + b.x;
    p[4 * k + 1] = a.y + b.y;
    p[4 * k + 2] = a.z + b.z;
    p[4 * k + 3] = a.w + b.w;
  }
}

// ---------------------------------------------------------------------------
// Main: one block per (b,f), 128 threads (2 waves), 8 frames/thread.
// Stage-fusion (36 -> 15 barrier stages, see round-3 derivation):
//  - type-1: all 4 sweeps from ONE 64-real Gram reduction + rank-1 H
//    recurrence; X-update applied once via accumulated 4x4 complex M.
//  - type-2: both taps per src from ONE 32-real reduction.
// __launch_bounds__(128, 1): empirical VGPR cap on this toolchain is
// 256/waves_per_eu_arg — (256,4)->64+spill, (128,2)->128 (spilled at need
// ~210, round 4), (256,2)->128. Fused kernel peaks ~200 live regs, so arg=1
// (cap 256). Occupancy unaffected: ~210 VGPR still gives 2 waves/SIMD and
// residency is grid-limited (~4 blocks/CU) regardless.
// ---------------------------------------------------------------------------
__global__ __launch_bounds__(128, 1) void k_main(const float* __restrict__ Xr,
                                                 const float* __restrict__ Xi,
                                                 float* __restrict__ out, int nout) {
  const int blk = blockIdx.x;
  const int b = blk / NF, f = blk % NF;
  const int tid = threadIdx.x;            // 0..127
  const int lane = tid & 63, wvid = tid >> 6;
  const float invN = 1.f / (float)NFR;

  __shared__ float red[2][2][64];
  __shared__ float Wre[NC][NC], Wim[NC][NC];
  __shared__ float abc[8];

  v2f xcr[NC][4], xci[NC][4];
  int rowbase[NC];
#pragma unroll
  for (int c = 0; c < NC; ++c) {
    rowbase[c] = ((b * NC + c) * NF + f) * NFR;
    const float4* pr = reinterpret_cast<const float4*>(Xr + rowbase[c]);
    const float4* pi = reinterpret_cast<const float4*>(Xi + rowbase[c]);
    float4 a0 = pr[2 * tid], a1 = pr[2 * tid + 1];
    float4 b0 = pi[2 * tid], b1 = pi[2 * tid + 1];
    xcr[c][0] = (v2f){a0.x, a0.y}; xcr[c][1] = (v2f){a0.z, a0.w};
    xcr[c][2] = (v2f){a1.x, a1.y}; xcr[c][3] = (v2f){a1.z, a1.w};
    xci[c][0] = (v2f){b0.x, b0.y}; xci[c][1] = (v2f){b0.z, b0.w};
    xci[c][2] = (v2f){b1.x, b1.y}; xci[c][3] = (v2f){b1.z, b1.w};
  }
  if (tid < 16) {
    Wre[tid >> 2][tid & 3] = ((tid >> 2) == (tid & 3)) ? 1.f : 0.f;
    Wim[tid >> 2][tid & 3] = 0.f;
  }
  // W-init visibility to thread 0: ordered by the first stage's barrier.

  v2f w2[NC][4];
  int buf = 0;

  for (int e = 0; e < 3; ++e) {
    // ---- per-epoch weights: w = g * rcp(max(2*sqrt(S/P), eps)) ----
#pragma unroll
    for (int c = 0; c < NC; ++c) {
      float g = g_gP[e * 32 + b * NC + c];
      float P = g_gP[e * 32 + 16 + b * NC + c];
      float sc = __builtin_amdgcn_rcpf(P);
      const float4* ps = reinterpret_cast<const float4*>(g_S + (b * NC + c) * NFR);
      float4 S0 = ps[2 * tid], S1 = ps[2 * tid + 1];
      float sv[8] = {S0.x, S0.y, S0.z, S0.w, S1.x, S1.y, S1.z, S1.w};
      float wv[8];
#pragma unroll
      for (int j = 0; j < 8; ++j)
        wv[j] = g * __builtin_amdgcn_rcpf(fmaxf(2.f * __builtin_amdgcn_sqrtf(sv[j] * sc), EPS_MODEL));
#pragma unroll
      for (int h = 0; h < 4; ++h) w2[c][h] = (v2f){wv[2 * h], wv[2 * h + 1]};
    }

    // ================= stage A: fused type-1 (one 64-real reduction) =======
    {
      // Layout: hs[c*16 + s]        = HD[c][s]  (diag, real)
      //         hs[c*16 + 4 + 2q]   = Re H[c][pair q]   (s<t)
      //         hs[c*16 + 4 + 2q+1] = Im H[c][pair q]
      float hs[64];
#pragma unroll
      for (int k = 0; k < 64; ++k) hs[k] = 0.f;
#pragma unroll
      for (int h = 0; h < 4; ++h) {
#pragma unroll
        for (int half = 0; half < 2; ++half) {
          float xr[4], xi[4], wv[4];
#pragma unroll
          for (int s = 0; s < 4; ++s) {
            xr[s] = half ? xcr[s][h].y : xcr[s][h].x;
            xi[s] = half ? xci[s][h].y : xci[s][h].x;
            wv[s] = half ? w2[s][h].y : w2[s][h].x;
          }
          float Pd[4], Pr[6], Pi[6];
#pragma unroll
          for (int s = 0; s < 4; ++s) Pd[s] = xr[s] * xr[s] + xi[s] * xi[s];
#pragma unroll
          for (int s = 0; s < 4; ++s)
#pragma unroll
            for (int t = s + 1; t < 4; ++t) {
              const int q = PIDX(s, t);
              Pr[q] = xr[s] * xr[t] + xi[s] * xi[t];
              Pi[q] = xi[s] * xr[t] - xr[s] * xi[t];
            }
#pragma unroll
          for (int c = 0; c < 4; ++c) {
#pragma unroll
            for (int s = 0; s < 4; ++s) hs[c * 16 + s] += wv[c] * Pd[s];
#pragma unroll
            for (int q = 0; q < 6; ++q) {
              hs[c * 16 + 4 + 2 * q]     += wv[c] * Pr[q];
              hs[c * 16 + 4 + 2 * q + 1] += wv[c] * Pi[q];
            }
          }
        }
      }
      block_reduceN<64>(hs, red, buf, lane, wvid);
      buf ^= 1;

      // ---- 4 sweeps via H recurrence; accumulate M = E3 E2 E1 E0 ----
      float Mr[4][4], Mi[4][4];
#pragma unroll
      for (int i = 0; i < 4; ++i)
#pragma unroll
        for (int j = 0; j < 4; ++j) { Mr[i][j] = (i == j) ? 1.f : 0.f; Mi[i][j] = 0.f; }

#pragma unroll
      for (int src = 0; src < 4; ++src) {
        float vr[4], vi[4];
#pragma unroll
        for (int c = 0; c < 4; ++c) {
          float den = fmaxf(hs[c * 16 + src] * invN, EPSV);
          if (c == src) {
            vr[c] = 1.f - __builtin_amdgcn_rsqf(den);
            vi[c] = 0.f;
          } else {
            float nr, ni;
            if (c < src) { const int q = PIDX(c, src); nr = hs[c * 16 + 4 + 2 * q]; ni = hs[c * 16 + 4 + 2 * q + 1]; }
            else         { const int q = PIDX(src, c); nr = hs[c * 16 + 4 + 2 * q]; ni = -hs[c * 16 + 4 + 2 * q + 1]; }
            float sc = invN * __builtin_amdgcn_rcpf(den);
            vr[c] = nr * sc; vi[c] = ni * sc;
          }
        }
        // M <- (I - v e_src^T) M, using the OLD row src
        float msr[4], msi[4];
#pragma unroll
        for (int j = 0; j < 4; ++j) { msr[j] = Mr[src][j]; msi[j] = Mi[src][j]; }
#pragma unroll
        for (int c = 0; c < 4; ++c)
#pragma unroll
          for (int j = 0; j < 4; ++j) {
            Mr[c][j] -= vr[c] * msr[j] - vi[c] * msi[j];
            Mi[c][j] -= vr[c] * msi[j] + vi[c] * msr[j];
          }
        // H rank-1 recurrence (skip after last sweep):
        // H'[c,s,t] = H - conj(v[t])*col[s] - v[s]*conj(col[t]) + v[s]conj(v[t])*d
        if (src < 3) {
#pragma unroll
          for (int c = 0; c < 4; ++c) {
            const float d = hs[c * 16 + src];
            float colr[4], coli[4];  // col[s] = H[c,s,src]
#pragma unroll
            for (int s = 0; s < 4; ++s) {
              if (s == src)      { colr[s] = d; coli[s] = 0.f; }
              else if (s < src)  { const int q = PIDX(s, src); colr[s] = hs[c * 16 + 4 + 2 * q]; coli[s] = hs[c * 16 + 4 + 2 * q + 1]; }
              else               { const int q = PIDX(src, s); colr[s] = hs[c * 16 + 4 + 2 * q]; coli[s] = -hs[c * 16 + 4 + 2 * q + 1]; }
            }
#pragma unroll
            for (int s = 0; s < 4; ++s)
              hs[c * 16 + s] += -2.f * (vr[s] * colr[s] + vi[s] * coli[s])
                                + (vr[s] * vr[s] + vi[s] * vi[s]) * d;
#pragma unroll
            for (int s = 0; s < 4; ++s)
#pragma unroll
              for (int t = s + 1; t < 4; ++t) {
                const int q = PIDX(s, t);
                float hr = hs[c * 16 + 4 + 2 * q], hi = hs[c * 16 + 4 + 2 * q + 1];
                hr -= vr[t] * colr[s] + vi[t] * coli[s];
                hi -= vr[t] * coli[s] - vi[t] * colr[s];
                hr -= vr[s] * colr[t] + vi[s] * coli[t];
                hi -= vi[s] * colr[t] - vr[s] * coli[t];
                float prr = vr[s] * vr[t] + vi[s] * vi[t];
                float pii = vi[s] * vr[t] - vr[s] * vi[t];
                hr += prr * d; hi += pii * d;
                hs[c * 16 + 4 + 2 * q] = hr; hs[c * 16 + 4 + 2 * q + 1] = hi;
              }
          }
        }
      }

      // ---- apply M to Xc registers (one pass) ----
#pragma unroll
      for (int h = 0; h < 4; ++h) {
        v2f nr[4], ni[4];
#pragma unroll
        for (int c = 0; c < 4; ++c) {
          nr[c] = (v2f){0.f, 0.f}; ni[c] = (v2f){0.f, 0.f};
#pragma unroll
          for (int s = 0; s < 4; ++s) {
            nr[c] += Mr[c][s] * xcr[s][h] - Mi[c][s] * xci[s][h];
            ni[c] += Mr[c][s] * xci[s][h] + Mi[c][s] * xcr[s][h];
          }
        }
#pragma unroll
        for (int c = 0; c < 4; ++c) { xcr[c][h] = nr[c]; xci[c][h] = ni[c]; }
      }

      // ---- W <- M * W once per epoch (tid 0; uniform M) ----
      if (tid == 0) {
        float nWr[4][4], nWi[4][4];
#pragma unroll
        for (int c = 0; c < 4; ++c)
#pragma unroll
          for (int j = 0; j < 4; ++j) {
            float sr = 0.f, si = 0.f;
#pragma unroll
            for (int s = 0; s < 4; ++s) {
              sr += Mr[c][s] * Wre[s][j] - Mi[c][s] * Wim[s][j];
              si += Mr[c][s] * Wim[s][j] + Mi[c][s] * Wre[s][j];
            }
            nWr[c][j] = sr; nWi[c][j] = si;
          }
#pragma unroll
        for (int c = 0; c < 4; ++c)
#pragma unroll
          for (int j = 0; j < 4; ++j) { Wre[c][j] = nWr[c][j]; Wim[c][j] = nWi[c][j]; }
      }
    }

    // ============ stage B x4: fused type-2 (one 32-real reduction/src) =====
#pragma unroll
    for (int src = 0; src < NC; ++src) {
      const float4* pr = reinterpret_cast<const float4*>(Xr + rowbase[src]);
      const float4* pi = reinterpret_cast<const float4*>(Xi + rowbase[src]);
      // 9-frame window [8t-3 .. 8t+5] of ORIGINAL X serves both taps.
      float4 A4r = make_float4(0.f, 0.f, 0.f, 0.f), A4i = A4r;
      if (tid > 0) { A4r = pr[2 * tid - 1]; A4i = pi[2 * tid - 1]; }
      float4 B4r = pr[2 * tid], B4i = pi[2 * tid];
      float4 C4r = pr[2 * tid + 1], C4i = pi[2 * tid + 1];
      float wr[9] = {A4r.y, A4r.z, A4r.w, B4r.x, B4r.y, B4r.z, B4r.w, C4r.x, C4r.y};
      float wi[9] = {A4i.y, A4i.z, A4i.w, B4i.x, B4i.y, B4i.z, B4i.w, C4i.x, C4i.y};

      // stats layout: [0+c]=N0r [4+c]=N0i [8+c]=N1r [12+c]=N1i
      //               [16+c]=D0 [20+c]=D1 [24+c]=C01r [28+c]=C01i
      // Scalar accumulators (32 regs, not 64): fold the two v2f halves with
      // two FMAs per term, halving live accumulator footprint.
      float p[32];
#pragma unroll
      for (int k = 0; k < 32; ++k) p[k] = 0.f;
#pragma unroll
      for (int h = 0; h < 4; ++h) {
        v2f y0r = (v2f){wr[2 * h], wr[2 * h + 1]};
        v2f y0i = (v2f){wi[2 * h], wi[2 * h + 1]};
        v2f y1r = (v2f){wr[2 * h + 1], wr[2 * h + 2]};
        v2f y1i = (v2f){wi[2 * h + 1], wi[2 * h + 2]};
        v2f m0 = y0r * y0r + y0i * y0i;
        v2f m1 = y1r * y1r + y1i * y1i;
        v2f zr = y0r * y1r + y0i * y1i;  // Y0 * conj(Y1)
        v2f zi = y0i * y1r - y0r * y1i;
#pragma unroll
        for (int c = 0; c < NC; ++c) {
          v2f wv = w2[c][h];
          v2f t;
          t = xcr[c][h] * y0r + xci[c][h] * y0i;
          p[c]      += wv.x * t.x + wv.y * t.y;
          t = xci[c][h] * y0r - xcr[c][h] * y0i;
          p[4 + c]  += wv.x * t.x + wv.y * t.y;
          t = xcr[c][h] * y1r + xci[c][h] * y1i;
          p[8 + c]  += wv.x * t.x + wv.y * t.y;
          t = xci[c][h] * y1r - xcr[c][h] * y1i;
          p[12 + c] += wv.x * t.x + wv.y * t.y;
          p[16 + c] += wv.x * m0.x + wv.y * m0.y;
          p[20 + c] += wv.x * m1.x + wv.y * m1.y;
          p[24 + c] += wv.x * zr.x + wv.y * zr.y;
          p[28 + c] += wv.x * zi.x + wv.y * zi.y;
        }
      }
      block_reduceN<32>(p, red, buf, lane, wvid);
      buf ^= 1;

      float v0r[4], v0i[4], v1r[4], v1i[4];
#pragma unroll
      for (int c = 0; c < NC; ++c) {
        float sc0 = invN * __builtin_amdgcn_rcpf(fmaxf(p[16 + c], EPSV));
        v0r[c] = p[c] * sc0;
        v0i[c] = p[4 + c] * sc0;
        float n1r = p[8 + c]  - (v0r[c] * p[24 + c] - v0i[c] * p[28 + c]);
        float n1i = p[12 + c] - (v0r[c] * p[28 + c] + v0i[c] * p[24 + c]);
        float sc1 = invN * __builtin_amdgcn_rcpf(fmaxf(p[20 + c], EPSV));
        v1r[c] = n1r * sc1;
        v1i[c] = n1i * sc1;
      }
#pragma unroll
      for (int h = 0; h < 4; ++h) {
        v2f y0r = (v2f){wr[2 * h], wr[2 * h + 1]};
        v2f y0i = (v2f){wi[2 * h], wi[2 * h + 1]};
        v2f y1r = (v2f){wr[2 * h + 1], wr[2 * h + 2]};
        v2f y1i = (v2f){wi[2 * h + 1], wi[2 * h + 2]};
#pragma unroll
        for (int c = 0; c < NC; ++c) {
          xcr[c][h] -= y0r * v0r[c] - y0i * v0i[c] + y1r * v1r[c] - y1i * v1i[c];
          xci[c][h] -= y0i * v0r[c] + y0r * v0i[c] + y1i * v1r[c] + y1r * v1i[c];
        }
      }
    }
  }  // epochs

  // ---- solve W^T a = e1 (4x4 complex, partial pivoting), A[i][j] = W[j][i] ----
  __syncthreads();
  if (tid == 0) {
    float Ar[4][4], Ai[4][4];
    float br[4] = {1.f, 0.f, 0.f, 0.f}, bi[4] = {0.f, 0.f, 0.f, 0.f};
#pragma unroll
    for (int i = 0; i < 4; ++i)
#pragma unroll
      for (int j = 0; j < 4; ++j) {
        Ar[i][j] = Wre[j][i];
        Ai[i][j] = Wim[j][i];
      }
    for (int k = 0; k < 4; ++k) {
      int piv = k;
      float best = Ar[k][k] * Ar[k][k] + Ai[k][k] * Ai[k][k];
      for (int i = k + 1; i < 4; ++i) {
        float m = Ar[i][k] * Ar[i][k] + Ai[i][k] * Ai[i][k];
        if (m > best) { best = m; piv = i; }
      }
      if (piv != k) {
        for (int j = 0; j < 4; ++j) {
          float t = Ar[k][j]; Ar[k][j] = Ar[piv][j]; Ar[piv][j] = t;
          t = Ai[k][j]; Ai[k][j] = Ai[piv][j]; Ai[piv][j] = t;
        }
        float t = br[k]; br[k] = br[piv]; br[piv] = t;
        t = bi[k]; bi[k] = bi[piv]; bi[piv] = t;
      }
      float dr = Ar[k][k], di = Ai[k][k];
      float inv = 1.f / (dr * dr + di * di);
      for (int i = k + 1; i < 4; ++i) {
        float fr = (Ar[i][k] * dr + Ai[i][k] * di) * inv;
        float fi = (Ai[i][k] * dr - Ar[i][k] * di) * inv;
        for (int j = k; j < 4; ++j) {
          Ar[i][j] -= fr * Ar[k][j] - fi * Ai[k][j];
          Ai[i][j] -= fr * Ai[k][j] + fi * Ar[k][j];
        }
        br[i] -= fr * br[k] - fi * bi[k];
        bi[i] -= fr * bi[k] + fi * br[k];
      }
    }
    float ar[4], ai[4];
    for (int k = 3; k >= 0; --k) {
      float sr = br[k], si = bi[k];
      for (int j = k + 1; j < 4; ++j) {
        sr -= Ar[k][j] * ar[j] - Ai[k][j] * ai[j];
        si -= Ar[k][j] * ai[j] + Ai[k][j] * ar[j];
      }
      float dr = Ar[k][k], di = Ai[k][k];
      float inv = 1.f / (dr * dr + di * di);
      ar[k] = (sr * dr + si * di) * inv;
      ai[k] = (si * dr - sr * di) * inv;
    }
#pragma unroll
    for (int c = 0; c < 4; ++c) { abc[c] = ar[c]; abc[4 + c] = ai[c]; }
  }
  __syncthreads();

  // ---- output: real(Xc * a), 2x float4 per (c, thread), bounds-guarded ----
#pragma unroll
  for (int c = 0; c < NC; ++c) {
    float ar = abc[c], ai2 = abc[4 + c];
    if (rowbase[c] + 8 * tid + 7 < nout) {
      float4* po = reinterpret_cast<float4*>(out + rowbase[c]);
      v2f o0 = xcr[c][0] * ar - xci[c][0] * ai2;
      v2f o1 = xcr[c][1] * ar - xci[c][1] * ai2;
      v2f o2 = xcr[c][2] * ar - xci[c][2] * ai2;
      v2f o3 = xcr[c][3] * ar - xci[c][3] * ai2;
      po[2 * tid]     = make_float4(o0.x, o0.y, o1.x, o1.y);
      po[2 * tid + 1] = make_float4(o2.x, o2.y, o3.x, o3.y);
    }
  }
}

// ---------------------------------------------------------------------------
extern "C" void kernel_launch(void* const* d_in, const int* in_sizes, int n_in,
                              void* d_out, int out_size, void* d_ws, size_t ws_size,
                              hipStream_t stream) {
  const float* Xr = (const float*)d_in[0];
  const float* Xi = (const float*)d_in[1];
  float* out = (float*)d_out;

  dim3 g1(16, NCHUNK);
  k_colsum<<<g1, 256, 0, stream>>>(Xr, Xi);
  k_redgp<<<16, 256, 0, stream>>>();
  k_main<<<NB * NF, 128, 0, stream>>>(Xr, Xi, out, out_size);
}

// Round 6
// 257.862 us; speedup vs baseline: 1.2960x; 1.2960x over previous
//
#include <hip/hip_runtime.h>
#include <math.h>

#define NB 4
#define NC 4
#define NF 257
#define NFR 1024
#define NTOT (NB * NC * NF * NFR)
#define NBC (NB * NC)
#define EPSV 1e-3f
#define EPS_MODEL 1e-5f
#define NCHUNK 32

typedef float v2f __attribute__((ext_vector_type(2)));

// Module-scope scratch: allocated at load, graph-capture safe, fully
// rewritten every call.
__device__ float g_Spart[NCHUNK * NBC * NFR];  // partial column sums
__device__ float g_S[NBC * NFR];               // S[b,c,n] = sum_f |X[b,c,f,n]|^2
__device__ float g_gP[96];                     // g_e, P_e per (b,c), e=0..2

// Wave-wide sum via DPP (VALU pipe, no LDS traffic). Lane 63 holds the sum.
__device__ __forceinline__ float dpp_red_sum(float v) {
  v += __int_as_float(__builtin_amdgcn_update_dpp(0, __float_as_int(v), 0x111, 0xf, 0xf, true)); // row_shr:1
  v += __int_as_float(__builtin_amdgcn_update_dpp(0, __float_as_int(v), 0x112, 0xf, 0xf, true)); // row_shr:2
  v += __int_as_float(__builtin_amdgcn_update_dpp(0, __float_as_int(v), 0x114, 0xf, 0xf, true)); // row_shr:4
  v += __int_as_float(__builtin_amdgcn_update_dpp(0, __float_as_int(v), 0x118, 0xf, 0xf, true)); // row_shr:8
  v += __int_as_float(__builtin_amdgcn_update_dpp(0, __float_as_int(v), 0x142, 0xa, 0xf, true)); // row_bcast:15
  v += __int_as_float(__builtin_amdgcn_update_dpp(0, __float_as_int(v), 0x143, 0xc, 0xf, true)); // row_bcast:31
  return v;
}

// ---------------------------------------------------------------------------
// K1: partial column sums, float4-vectorized, 512 blocks (full GPU).
// ---------------------------------------------------------------------------
__global__ __launch_bounds__(256) void k_colsum(const float* __restrict__ Xr,
                                                const float* __restrict__ Xi) {
  int u = blockIdx.x * 256 + threadIdx.x;  // bc*256 + q
  int fc = blockIdx.y;
  int f0 = fc * 9;
  int f1 = f0 + 9; if (f1 > NF) f1 = NF;
  int bc = u >> 8, q = u & 255;
  float4 s = make_float4(0.f, 0.f, 0.f, 0.f);
  for (int f = f0; f < f1; ++f) {
    float4 a = reinterpret_cast<const float4*>(Xr + (bc * NF + f) * NFR)[q];
    float4 b = reinterpret_cast<const float4*>(Xi + (bc * NF + f) * NFR)[q];
    s.x += a.x * a.x + b.x * b.x;
    s.y += a.y * a.y + b.y * b.y;
    s.z += a.z * a.z + b.z * b.z;
    s.w += a.w * a.w + b.w * b.w;
  }
  reinterpret_cast<float4*>(g_Spart + fc * (NBC * NFR) + bc * NFR)[q] = s;
}

// ---------------------------------------------------------------------------
// K2 (fused): reduce 32 partials -> g_S; block-reduce to s0; g_e/P_e table.
// ---------------------------------------------------------------------------
__global__ __launch_bounds__(256) void k_redgp() {
  int bc = blockIdx.x, tid = threadIdx.x;
  float4 s = make_float4(0.f, 0.f, 0.f, 0.f);
#pragma unroll
  for (int fc = 0; fc < NCHUNK; ++fc) {
    float4 a = reinterpret_cast<const float4*>(g_Spart + fc * (NBC * NFR) + bc * NFR)[tid];
    s.x += a.x; s.y += a.y; s.z += a.z; s.w += a.w;
  }
  reinterpret_cast<float4*>(g_S + bc * NFR)[tid] = s;
  float p = dpp_red_sum(s.x + s.y + s.z + s.w);
  __shared__ float r[4];
  if ((tid & 63) == 63) r[tid >> 6] = p;
  __syncthreads();
  if (tid == 0) {
    float s0 = (r[0] + r[1] + r[2] + r[3]) / (float)(NF * NFR);
    float P = 1.f;
#pragma unroll
    for (int e = 0; e < 3; ++e) {
      float g = fmaxf(s0 / P, 1e-5f);
      g_gP[e * 32 + bc] = g;
      g_gP[e * 32 + 16 + bc] = P;
      P *= g;
    }
  }
}

// Block-level reduction of 32 partials (in place), 2-wave version: DPP within
// wave, one barrier, b128 LDS round-trip, double-buffered via `buf`.
__device__ __forceinline__ void block_reduce32(float* p, float (*red)[2][32],
                                               int buf, int lane, int wvid) {
#pragma unroll
  for (int k = 0; k < 32; ++k) p[k] = dpp_red_sum(p[k]);
  if (lane == 63) {
    float4* dst = reinterpret_cast<float4*>(&red[buf][wvid][0]);
#pragma unroll
    for (int k = 0; k < 8; ++k)
      dst[k] = make_float4(p[4 * k], p[4 * k + 1], p[4 * k + 2], p[4 * k + 3]);
  }
  __syncthreads();
  const float4* r0 = reinterpret_cast<const float4*>(&red[buf][0][0]);
  const float4* r1 = reinterpret_cast<const float4*>(&red[buf][1][0]);
#pragma unroll
  for (int k = 0; k < 8; ++k) {
    float4 a = r0[k], b = r1[k];
    p[4 * k + 0] = a.x + b.x;
    p[4 * k + 1] = a.y + b.y;
    p[4 * k + 2] = a.z + b.z;
    p[4 * k + 3] = a.w + b.w;
  }
}

// ---------------------------------------------------------------------------
// Fused type-1 PAIR sweep (s0 then s1) from ONE 32-real reduction.
// Stats over current X: A=Sum w[c] X_c conj(Xs0), B=.. conj(Xs1),
// C=Sum w[c] Xs0 conj(Xs1), D0=Sum w[c]|Xs0|^2, D1=Sum w[c]|Xs1|^2.
// Sweep s0: v0 from A,D0.  Sweep s1 on updated data via correction:
//   a = v0[s1]
//   num1[c] = B - conj(a) A - v0c C + v0c conj(a) D0
//   den1[c] = D1 - 2 Re(a C) + |a|^2 D0
// Fused update: X_c -= u0c Xs0 + u1c Xs1, u0 = v0 - v1 a, u1 = v1.
// W rows s0,s1 same combined form. Peak live across barrier ~150 regs.
// ---------------------------------------------------------------------------
template <int S0, int S1>
__device__ __forceinline__ void t1_pair(v2f (&xcr)[NC][4], v2f (&xci)[NC][4],
                                        v2f (&w2)[NC][4],
                                        float (&Wre)[NC][NC], float (&Wim)[NC][NC],
                                        float (*red)[2][32], int& buf,
                                        int lane, int wvid, int tid, float invN) {
  float p[32];
#pragma unroll
  for (int k = 0; k < 32; ++k) p[k] = 0.f;
#pragma unroll
  for (int h = 0; h < 4; ++h) {
    v2f y0r = xcr[S0][h], y0i = xci[S0][h];
    v2f y1r = xcr[S1][h], y1i = xci[S1][h];
    v2f m0 = y0r * y0r + y0i * y0i;
    v2f m1 = y1r * y1r + y1i * y1i;
    v2f zr = y0r * y1r + y0i * y1i;  // Y0 * conj(Y1)
    v2f zi = y0i * y1r - y0r * y1i;
#pragma unroll
    for (int c = 0; c < NC; ++c) {
      v2f wv = w2[c][h];
      v2f t;
      t = xcr[c][h] * y0r + xci[c][h] * y0i;  p[c]      += wv.x * t.x + wv.y * t.y;
      t = xci[c][h] * y0r - xcr[c][h] * y0i;  p[4 + c]  += wv.x * t.x + wv.y * t.y;
      t = xcr[c][h] * y1r + xci[c][h] * y1i;  p[8 + c]  += wv.x * t.x + wv.y * t.y;
      t = xci[c][h] * y1r - xcr[c][h] * y1i;  p[12 + c] += wv.x * t.x + wv.y * t.y;
      p[16 + c] += wv.x * m0.x + wv.y * m0.y;
      p[20 + c] += wv.x * m1.x + wv.y * m1.y;
      p[24 + c] += wv.x * zr.x + wv.y * zr.y;
      p[28 + c] += wv.x * zi.x + wv.y * zi.y;
    }
  }
  block_reduce32(p, red, buf, lane, wvid);
  buf ^= 1;

  // ---- sweep s0 (type-1 semantics: mean denominators) ----
  float v0r[4], v0i[4];
#pragma unroll
  for (int c = 0; c < 4; ++c) {
    float den = fmaxf(p[16 + c] * invN, EPSV);
    if (c == S0) {
      v0r[c] = 1.f - __builtin_amdgcn_rsqf(den);
      v0i[c] = 0.f;
    } else {
      float sc = invN * __builtin_amdgcn_rcpf(den);
      v0r[c] = p[c] * sc;
      v0i[c] = p[4 + c] * sc;
    }
  }
  const float ar = v0r[S1], ai = v0i[S1];
  const float amag = ar * ar + ai * ai;

  // ---- sweep s1 via corrected stats ----
  float v1r[4], v1i[4];
#pragma unroll
  for (int c = 0; c < 4; ++c) {
    float den1 = p[20 + c] - 2.f * (ar * p[24 + c] - ai * p[28 + c]) + amag * p[16 + c];
    float den = fmaxf(den1 * invN, EPSV);
    if (c == S1) {
      v1r[c] = 1.f - __builtin_amdgcn_rsqf(den);
      v1i[c] = 0.f;
    } else {
      // conj(a)*A: Re = ar*Ar + ai*Ai, Im = ar*Ai - ai*Ar
      // v0c*C:     Re = v0r*Cr - v0i*Ci, Im = v0r*Ci + v0i*Cr
      // v0c*conj(a): Re = v0r*ar + v0i*ai, Im = v0i*ar - v0r*ai
      float nr = p[8 + c]  - (ar * p[c] + ai * p[4 + c])
                 - (v0r[c] * p[24 + c] - v0i[c] * p[28 + c])
                 + (v0r[c] * ar + v0i[c] * ai) * p[16 + c];
      float ni = p[12 + c] - (ar * p[4 + c] - ai * p[c])
                 - (v0r[c] * p[28 + c] + v0i[c] * p[24 + c])
                 + (v0i[c] * ar - v0r[c] * ai) * p[16 + c];
      float sc = invN * __builtin_amdgcn_rcpf(den);
      v1r[c] = nr * sc;
      v1i[c] = ni * sc;
    }
  }

  // ---- combined coefficients: u0 = v0 - v1*a, u1 = v1 ----
  float u0r[4], u0i[4];
#pragma unroll
  for (int c = 0; c < 4; ++c) {
    u0r[c] = v0r[c] - (v1r[c] * ar - v1i[c] * ai);
    u0i[c] = v0i[c] - (v1r[c] * ai + v1i[c] * ar);
  }

  // ---- fused X update (snapshot Y rows per h before writing) ----
#pragma unroll
  for (int h = 0; h < 4; ++h) {
    v2f y0r = xcr[S0][h], y0i = xci[S0][h];
    v2f y1r = xcr[S1][h], y1i = xci[S1][h];
#pragma unroll
    for (int c = 0; c < NC; ++c) {
      xcr[c][h] -= y0r * u0r[c] - y0i * u0i[c] + y1r * v1r[c] - y1i * v1i[c];
      xci[c][h] -= y0i * u0r[c] + y0r * u0i[c] + y1i * v1r[c] + y1r * v1i[c];
    }
  }

  // ---- fused W update ----
  if (tid == 0) {
#pragma unroll
    for (int j = 0; j < NC; ++j) {
      float w0r = Wre[S0][j], w0i = Wim[S0][j];
      float w1r = Wre[S1][j], w1i = Wim[S1][j];
#pragma unroll
      for (int c = 0; c < NC; ++c) {
        Wre[c][j] -= u0r[c] * w0r - u0i[c] * w0i + v1r[c] * w1r - v1i[c] * w1i;
        Wim[c][j] -= u0r[c] * w0i + u0i[c] * w0r + v1r[c] * w1i + v1i[c] * w1r;
      }
    }
  }
}

// ---------------------------------------------------------------------------
// Fused type-2 stage (both taps of one src, round-5 verified algebra):
// one 32-real reduction; v1 numerator corrected by v0*C01; denominators SUM.
// ---------------------------------------------------------------------------
__device__ __forceinline__ void t2_stage(const float* __restrict__ prb,
                                         const float* __restrict__ pib,
                                         v2f (&xcr)[NC][4], v2f (&xci)[NC][4],
                                         v2f (&w2)[NC][4],
                                         float (*red)[2][32], int& buf,
                                         int lane, int wvid, int tid, float invN) {
  const float4* pr = reinterpret_cast<const float4*>(prb);
  const float4* pi = reinterpret_cast<const float4*>(pib);
  // 9-frame window [8t-3 .. 8t+5] of ORIGINAL X serves both taps.
  float4 A4r = make_float4(0.f, 0.f, 0.f, 0.f), A4i = A4r;
  if (tid > 0) { A4r = pr[2 * tid - 1]; A4i = pi[2 * tid - 1]; }
  float4 B4r = pr[2 * tid], B4i = pi[2 * tid];
  float4 C4r = pr[2 * tid + 1], C4i = pi[2 * tid + 1];
  float wr[9] = {A4r.y, A4r.z, A4r.w, B4r.x, B4r.y, B4r.z, B4r.w, C4r.x, C4r.y};
  float wi[9] = {A4i.y, A4i.z, A4i.w, B4i.x, B4i.y, B4i.z, B4i.w, C4i.x, C4i.y};

  // stats: [0+c]=N0r [4+c]=N0i [8+c]=N1r [12+c]=N1i
  //        [16+c]=D0 [20+c]=D1 [24+c]=C01r [28+c]=C01i
  float p[32];
#pragma unroll
  for (int k = 0; k < 32; ++k) p[k] = 0.f;
#pragma unroll
  for (int h = 0; h < 4; ++h) {
    v2f y0r = (v2f){wr[2 * h], wr[2 * h + 1]};
    v2f y0i = (v2f){wi[2 * h], wi[2 * h + 1]};
    v2f y1r = (v2f){wr[2 * h + 1], wr[2 * h + 2]};
    v2f y1i = (v2f){wi[2 * h + 1], wi[2 * h + 2]};
    v2f m0 = y0r * y0r + y0i * y0i;
    v2f m1 = y1r * y1r + y1i * y1i;
    v2f zr = y0r * y1r + y0i * y1i;  // Y0 * conj(Y1)
    v2f zi = y0i * y1r - y0r * y1i;
#pragma unroll
    for (int c = 0; c < NC; ++c) {
      v2f wv = w2[c][h];
      v2f t;
      t = xcr[c][h] * y0r + xci[c][h] * y0i;  p[c]      += wv.x * t.x + wv.y * t.y;
      t = xci[c][h] * y0r - xcr[c][h] * y0i;  p[4 + c]  += wv.x * t.x + wv.y * t.y;
      t = xcr[c][h] * y1r + xci[c][h] * y1i;  p[8 + c]  += wv.x * t.x + wv.y * t.y;
      t = xci[c][h] * y1r - xcr[c][h] * y1i;  p[12 + c] += wv.x * t.x + wv.y * t.y;
      p[16 + c] += wv.x * m0.x + wv.y * m0.y;
      p[20 + c] += wv.x * m1.x + wv.y * m1.y;
      p[24 + c] += wv.x * zr.x + wv.y * zr.y;
      p[28 + c] += wv.x * zi.x + wv.y * zi.y;
    }
  }
  block_reduce32(p, red, buf, lane, wvid);
  buf ^= 1;

  float v0r[4], v0i[4], v1r[4], v1i[4];
#pragma unroll
  for (int c = 0; c < NC; ++c) {
    float sc0 = invN * __builtin_amdgcn_rcpf(fmaxf(p[16 + c], EPSV));  // SUM denom
    v0r[c] = p[c] * sc0;
    v0i[c] = p[4 + c] * sc0;
    float n1r = p[8 + c]  - (v0r[c] * p[24 + c] - v0i[c] * p[28 + c]);
    float n1i = p[12 + c] - (v0r[c] * p[28 + c] + v0i[c] * p[24 + c]);
    float sc1 = invN * __builtin_amdgcn_rcpf(fmaxf(p[20 + c], EPSV));
    v1r[c] = n1r * sc1;
    v1i[c] = n1i * sc1;
  }
#pragma unroll
  for (int h = 0; h < 4; ++h) {
    v2f y0r = (v2f){wr[2 * h], wr[2 * h + 1]};
    v2f y0i = (v2f){wi[2 * h], wi[2 * h + 1]};
    v2f y1r = (v2f){wr[2 * h + 1], wr[2 * h + 2]};
    v2f y1i = (v2f){wi[2 * h + 1], wi[2 * h + 2]};
#pragma unroll
    for (int c = 0; c < NC; ++c) {
      xcr[c][h] -= y0r * v0r[c] - y0i * v0i[c] + y1r * v1r[c] - y1i * v1i[c];
      xci[c][h] -= y0i * v0r[c] + y0r * v0i[c] + y1i * v1r[c] + y1r * v1i[c];
    }
  }
}

// ---------------------------------------------------------------------------
// Main: one block per (b,f), 128 threads (2 waves), 8 frames/thread (round-0
// base). Pair-fusion everywhere: every barrier stage is the SAME 32-real
// reduction shape (peak live ~150 regs, no spill — rounds 4/5 showed stages
// with >190 live regs spill and lose).
//   type-1: sweeps (0,1) and (2,3) pair-fused -> 2 stages
//   type-2: both taps per src fused          -> 4 stages
// Stages per epoch 12 -> 6; total 36 -> 18.
// __launch_bounds__(128,1): VGPR cap 256 (empirical cap = 256/min-waves arg).
// Occupancy is grid-limited (~4 blk/CU, 2 waves each) regardless.
// ---------------------------------------------------------------------------
__global__ __launch_bounds__(128, 1) void k_main(const float* __restrict__ Xr,
                                                 const float* __restrict__ Xi,
                                                 float* __restrict__ out, int nout) {
  const int blk = blockIdx.x;
  const int b = blk / NF, f = blk % NF;
  const int tid = threadIdx.x;            // 0..127
  const int lane = tid & 63, wvid = tid >> 6;
  const float invN = 1.f / (float)NFR;

  __shared__ float red[2][2][32];
  __shared__ float Wre[NC][NC], Wim[NC][NC];
  __shared__ float abc[8];

  v2f xcr[NC][4], xci[NC][4];
  int rowbase[NC];
#pragma unroll
  for (int c = 0; c < NC; ++c) {
    rowbase[c] = ((b * NC + c) * NF + f) * NFR;
    const float4* pr = reinterpret_cast<const float4*>(Xr + rowbase[c]);
    const float4* pi = reinterpret_cast<const float4*>(Xi + rowbase[c]);
    float4 a0 = pr[2 * tid], a1 = pr[2 * tid + 1];
    float4 b0 = pi[2 * tid], b1 = pi[2 * tid + 1];
    xcr[c][0] = (v2f){a0.x, a0.y}; xcr[c][1] = (v2f){a0.z, a0.w};
    xcr[c][2] = (v2f){a1.x, a1.y}; xcr[c][3] = (v2f){a1.z, a1.w};
    xci[c][0] = (v2f){b0.x, b0.y}; xci[c][1] = (v2f){b0.z, b0.w};
    xci[c][2] = (v2f){b1.x, b1.y}; xci[c][3] = (v2f){b1.z, b1.w};
  }
  if (tid < 16) {
    Wre[tid >> 2][tid & 3] = ((tid >> 2) == (tid & 3)) ? 1.f : 0.f;
    Wim[tid >> 2][tid & 3] = 0.f;
  }
  // W-init visibility to thread 0: ordered by the first stage's barrier.

  v2f w2[NC][4];
  int buf = 0;

  for (int e = 0; e < 3; ++e) {
    // ---- per-epoch weights: w = g * rcp(max(2*sqrt(S/P), eps)) ----
#pragma unroll
    for (int c = 0; c < NC; ++c) {
      float g = g_gP[e * 32 + b * NC + c];
      float P = g_gP[e * 32 + 16 + b * NC + c];
      float sc = __builtin_amdgcn_rcpf(P);
      const float4* ps = reinterpret_cast<const float4*>(g_S + (b * NC + c) * NFR);
      float4 S0 = ps[2 * tid], S1 = ps[2 * tid + 1];
      float sv[8] = {S0.x, S0.y, S0.z, S0.w, S1.x, S1.y, S1.z, S1.w};
      float wv[8];
#pragma unroll
      for (int j = 0; j < 8; ++j)
        wv[j] = g * __builtin_amdgcn_rcpf(fmaxf(2.f * __builtin_amdgcn_sqrtf(sv[j] * sc), EPS_MODEL));
#pragma unroll
      for (int h = 0; h < 4; ++h) w2[c][h] = (v2f){wv[2 * h], wv[2 * h + 1]};
    }

    // ---- type-1: two pair-fused stages ----
    t1_pair<0, 1>(xcr, xci, w2, Wre, Wim, red, buf, lane, wvid, tid, invN);
    t1_pair<2, 3>(xcr, xci, w2, Wre, Wim, red, buf, lane, wvid, tid, invN);

    // ---- type-2: four tap-fused stages ----
    t2_stage(Xr + rowbase[0], Xi + rowbase[0], xcr, xci, w2, red, buf, lane, wvid, tid, invN);
    t2_stage(Xr + rowbase[1], Xi + rowbase[1], xcr, xci, w2, red, buf, lane, wvid, tid, invN);
    t2_stage(Xr + rowbase[2], Xi + rowbase[2], xcr, xci, w2, red, buf, lane, wvid, tid, invN);
    t2_stage(Xr + rowbase[3], Xi + rowbase[3], xcr, xci, w2, red, buf, lane, wvid, tid, invN);
  }  // epochs

  // ---- solve W^T a = e1 (4x4 complex, partial pivoting), A[i][j] = W[j][i] ----
  __syncthreads();
  if (tid == 0) {
    float Ar[4][4], Ai[4][4];
    float br[4] = {1.f, 0.f, 0.f, 0.f}, bi[4] = {0.f, 0.f, 0.f, 0.f};
#pragma unroll
    for (int i = 0; i < 4; ++i)
#pragma unroll
      for (int j = 0; j < 4; ++j) {
        Ar[i][j] = Wre[j][i];
        Ai[i][j] = Wim[j][i];
      }
    for (int k = 0; k < 4; ++k) {
      int piv = k;
      float best = Ar[k][k] * Ar[k][k] + Ai[k][k] * Ai[k][k];
      for (int i = k + 1; i < 4; ++i) {
        float m = Ar[i][k] * Ar[i][k] + Ai[i][k] * Ai[i][k];
        if (m > best) { best = m; piv = i; }
      }
      if (piv != k) {
        for (int j = 0; j < 4; ++j) {
          float t = Ar[k][j]; Ar[k][j] = Ar[piv][j]; Ar[piv][j] = t;
          t = Ai[k][j]; Ai[k][j] = Ai[piv][j]; Ai[piv][j] = t;
        }
        float t = br[k]; br[k] = br[piv]; br[piv] = t;
        t = bi[k]; bi[k] = bi[piv]; bi[piv] = t;
      }
      float dr = Ar[k][k], di = Ai[k][k];
      float inv = 1.f / (dr * dr + di * di);
      for (int i = k + 1; i < 4; ++i) {
        float fr = (Ar[i][k] * dr + Ai[i][k] * di) * inv;
        float fi = (Ai[i][k] * dr - Ar[i][k] * di) * inv;
        for (int j = k; j < 4; ++j) {
          Ar[i][j] -= fr * Ar[k][j] - fi * Ai[k][j];
          Ai[i][j] -= fr * Ai[k][j] + fi * Ar[k][j];
        }
        br[i] -= fr * br[k] - fi * bi[k];
        bi[i] -= fr * bi[k] + fi * br[k];
      }
    }
    float ar[4], ai[4];
    for (int k = 3; k >= 0; --k) {
      float sr = br[k], si = bi[k];
      for (int j = k + 1; j < 4; ++j) {
        sr -= Ar[k][j] * ar[j] - Ai[k][j] * ai[j];
        si -= Ar[k][j] * ai[j] + Ai[k][j] * ar[j];
      }
      float dr = Ar[k][k], di = Ai[k][k];
      float inv = 1.f / (dr * dr + di * di);
      ar[k] = (sr * dr + si * di) * inv;
      ai[k] = (si * dr - sr * di) * inv;
    }
#pragma unroll
    for (int c = 0; c < 4; ++c) { abc[c] = ar[c]; abc[4 + c] = ai[c]; }
  }
  __syncthreads();

  // ---- output: real(Xc * a), 2x float4 per (c, thread), bounds-guarded ----
#pragma unroll
  for (int c = 0; c < NC; ++c) {
    float ar = abc[c], ai2 = abc[4 + c];
    if (rowbase[c] + 8 * tid + 7 < nout) {
      float4* po = reinterpret_cast<float4*>(out + rowbase[c]);
      v2f o0 = xcr[c][0] * ar - xci[c][0] * ai2;
      v2f o1 = xcr[c][1] * ar - xci[c][1] * ai2;
      v2f o2 = xcr[c][2] * ar - xci[c][2] * ai2;
      v2f o3 = xcr[c][3] * ar - xci[c][3] * ai2;
      po[2 * tid]     = make_float4(o0.x, o0.y, o1.x, o1.y);
      po[2 * tid + 1] = make_float4(o2.x, o2.y, o3.x, o3.y);
    }
  }
}

// ---------------------------------------------------------------------------
extern "C" void kernel_launch(void* const* d_in, const int* in_sizes, int n_in,
                              void* d_out, int out_size, void* d_ws, size_t ws_size,
                              hipStream_t stream) {
  const float* Xr = (const float*)d_in[0];
  const float* Xi = (const float*)d_in[1];
  float* out = (float*)d_out;

  dim3 g1(16, NCHUNK);
  k_colsum<<<g1, 256, 0, stream>>>(Xr, Xi);
  k_redgp<<<16, 256, 0, stream>>>();
  k_main<<<NB * NF, 128, 0, stream>>>(Xr, Xi, out, out_size);
}